// Round 13
// baseline (142.347 us; speedup 1.0000x reference)
//
#include <hip/hip_runtime.h>

#define N_NODES 10000
#define N_EDGES 320000
#define C_IN 128
#define C_OUT 128
#define KDIM 640            // 5 * 128

typedef __attribute__((ext_vector_type(8))) short short8;   // 8 bf16
typedef __attribute__((ext_vector_type(4))) float floatx4;  // MFMA C/D + nt loads
typedef __attribute__((ext_vector_type(2))) unsigned int uintx2;

// ---- bf16 helpers ---------------------------------------------------------
__device__ __forceinline__ unsigned short f2bf(float f) {
    unsigned int b = __float_as_uint(f);
    b = (b + 0x7FFFu + ((b >> 16) & 1u)) >> 16;   // RNE
    return (unsigned short)b;
}
__device__ __forceinline__ unsigned int pack2(float x, float y) {
    return (unsigned int)f2bf(x) | ((unsigned int)f2bf(y) << 16);
}
__device__ __forceinline__ float2 unpack2(unsigned int u) {
    float2 r;
    r.x = __uint_as_float(u << 16);
    r.y = __uint_as_float(u & 0xFFFF0000u);
    return r;
}

// ---------------------------------------------------------------------------
// Kernel 1 (prep): h->bf16, W->Wt bf16 transpose, CSR offsets (r11 verified).
// ---------------------------------------------------------------------------
__global__ __launch_bounds__(256) void prep(
        const float* __restrict__ h, uintx2* __restrict__ hb4,
        const float* __restrict__ W, unsigned short* __restrict__ Wt,
        const int* __restrict__ src, int* __restrict__ offsets) {
    const int bid = blockIdx.x;
    const int tid = threadIdx.x;

    if (bid < 1250) {                       // conv_h: 1250*256 = 320000 exact
        const int t = bid * 256 + tid;
        floatx4 v = __builtin_nontemporal_load(&((const floatx4*)h)[t]);
        uintx2 o;
        o.x = pack2(v.x, v.y);
        o.y = pack2(v.z, v.w);
        hb4[t] = o;
    } else if (bid < 1330) {                // conv_w transpose, 80 blocks
        __shared__ float tile[32][33];
        const int b = bid - 1250;
        const int k0 = (b % 20) * 32, o0 = (b / 20) * 32;
        const int tx = tid & 31, ty = tid >> 5;      // 32 x 8
#pragma unroll
        for (int i = 0; i < 4; ++i)
            tile[ty + 8 * i][tx] =
                __builtin_nontemporal_load(&W[(size_t)(k0 + ty + 8 * i) * C_OUT + o0 + tx]);
        __syncthreads();
#pragma unroll
        for (int i = 0; i < 4; ++i)
            Wt[(size_t)(o0 + ty + 8 * i) * KDIM + k0 + tx] = f2bf(tile[tx][ty + 8 * i]);
    } else {                                // offsets, 40 blocks
        const int n = (bid - 1330) * 256 + tid;
        if (n > N_NODES) return;
        int lo = 0, hi = N_EDGES;
        while (lo < hi) {
            int mid = (lo + hi) >> 1;
            if (src[mid] < n) lo = mid + 1; else hi = mid;
        }
        offsets[n] = lo;
    }
}

// ---------------------------------------------------------------------------
// Kernel 2 (scatter): IDENTICAL to rounds 11/12. Launched 3x as a timing
// instrument: dur = base + 2*S (idempotent, graph-capture safe).
// ---------------------------------------------------------------------------
__global__ __launch_bounds__(256) void scatter(
        const unsigned int* __restrict__ h2,   // (10000, 64) uint = 2 bf16 ch
        const float* __restrict__ X,           // (320000, 5)
        const int* __restrict__ dst,
        const int* __restrict__ offsets,
        unsigned int* __restrict__ R2) {       // (10000, 320) uint = bf16 pairs
    const int wv   = __builtin_amdgcn_readfirstlane(threadIdx.x >> 6);
    const int lane = threadIdx.x & 63;
    const int node = blockIdx.x * 4 + wv;      // 2500*4 = 10000 exact

    const int e0 = offsets[node];              // s_load (node scalar)
    const int e1 = offsets[node + 1];

    float a0x=0,a0y=0, a1x=0,a1y=0, a2x=0,a2y=0, a3x=0,a3y=0, a4x=0,a4y=0;

    int e = e0;
    for (; e + 7 < e1; e += 8) {               // scalar loop, unroll 8
        int d[8];
        unsigned int u[8];
#pragma unroll
        for (int q = 0; q < 8; ++q) d[q] = dst[e + q];        // s_loads
#pragma unroll
        for (int q = 0; q < 8; ++q)
            u[q] = h2[(size_t)d[q] * 64 + lane];              // 8 gathers in flight
#pragma unroll
        for (int q = 0; q < 8; ++q) {
            const float* Xp = X + (size_t)(e + q) * 5;        // s_loads
            const float x0 = Xp[0], x1 = Xp[1], x2 = Xp[2], x3 = Xp[3], x4 = Xp[4];
            const float2 hv = unpack2(u[q]);
            a0x = fmaf(x0, hv.x, a0x); a0y = fmaf(x0, hv.y, a0y);
            a1x = fmaf(x1, hv.x, a1x); a1y = fmaf(x1, hv.y, a1y);
            a2x = fmaf(x2, hv.x, a2x); a2y = fmaf(x2, hv.y, a2y);
            a3x = fmaf(x3, hv.x, a3x); a3y = fmaf(x3, hv.y, a3y);
            a4x = fmaf(x4, hv.x, a4x); a4y = fmaf(x4, hv.y, a4y);
        }
    }
    for (; e < e1; ++e) {                      // scalar tail
        const int d = dst[e];
        const unsigned int u = h2[(size_t)d * 64 + lane];
        const float* Xp = X + (size_t)e * 5;
        const float x0 = Xp[0], x1 = Xp[1], x2 = Xp[2], x3 = Xp[3], x4 = Xp[4];
        const float2 hv = unpack2(u);
        a0x = fmaf(x0, hv.x, a0x); a0y = fmaf(x0, hv.y, a0y);
        a1x = fmaf(x1, hv.x, a1x); a1y = fmaf(x1, hv.y, a1y);
        a2x = fmaf(x2, hv.x, a2x); a2y = fmaf(x2, hv.y, a2y);
        a3x = fmaf(x3, hv.x, a3x); a3y = fmaf(x3, hv.y, a3y);
        a4x = fmaf(x4, hv.x, a4x); a4y = fmaf(x4, hv.y, a4y);
    }

    unsigned int* Rn = R2 + (size_t)node * 320;
    Rn[0 * 64 + lane] = pack2(a0x, a0y);
    Rn[1 * 64 + lane] = pack2(a1x, a1y);
    Rn[2 * 64 + lane] = pack2(a2x, a2y);
    Rn[3 * 64 + lane] = pack2(a3x, a3y);
    Rn[4 * 64 + lane] = pack2(a4x, a4y);
}

// ---------------------------------------------------------------------------
// Kernel 3 (gemm16): TM=16, 625 blocks, 256 thr (4 waves).
// FIXED from round 12: each wave now computes TWO 16-col stripes
// (t = wv and t = wv+4) -> all 128 output columns covered (r12 covered
// only 0..63 -> absmax 40.5).
// Per 64-k chunk: As (16x64) + Bs (128x64) staged coalesced b128, pitch 66
// shorts (odd dword) -> <=2-way banks. 4 MFMA/chunk/wave, 40 total.
// D row=quad*4+r, col=lane&15 (verified rounds 3-11).
// ---------------------------------------------------------------------------
__global__ __launch_bounds__(256) void gemm16(
        const unsigned short* __restrict__ R,
        const unsigned short* __restrict__ Wt,
        const float* __restrict__ bias,
        float* __restrict__ out) {
    __shared__ unsigned short As[16][66];      // 2.1 KB
    __shared__ unsigned short Bs[128][66];     // 16.9 KB

    const int tid  = threadIdx.x;
    const int wv   = tid >> 6;
    const int lane = tid & 63;
    const int col  = lane & 15;
    const int quad = lane >> 4;
    const int m0   = blockIdx.x * 16;          // 625*16 = 10000 exact

    floatx4 acc0 = {0.f, 0.f, 0.f, 0.f};
    floatx4 acc1 = {0.f, 0.f, 0.f, 0.f};

    for (int chunk = 0; chunk < 10; ++chunk) {
        if (chunk) __syncthreads();
        // As: 16 rows x 64 bf16 = 128 b128 chunks; threads 0..127.
        if (tid < 128) {
            const int row = tid >> 3, c8 = tid & 7;
            *(short8*)&As[row][c8 * 8] =
                *(const short8*)(R + (size_t)(m0 + row) * KDIM + chunk * 64 + c8 * 8);
        }
        // Bs: 128 rows x 64 bf16 = 1024 b128 chunks, 4/thread, coalesced.
#pragma unroll
        for (int r = 0; r < 4; ++r) {
            const int c = r * 256 + tid;
            const int row = c >> 3, c8 = c & 7;
            *(short8*)&Bs[row][c8 * 8] =
                *(const short8*)(Wt + (size_t)row * KDIM + chunk * 64 + c8 * 8);
        }
        __syncthreads();

#pragma unroll
        for (int hh = 0; hh < 2; ++hh) {
            const short8 af = *(const short8*)&As[col][hh * 32 + quad * 8];
            const short8 bf0 = *(const short8*)&Bs[wv * 16 + col][hh * 32 + quad * 8];
            const short8 bf1 = *(const short8*)&Bs[(wv + 4) * 16 + col][hh * 32 + quad * 8];
            acc0 = __builtin_amdgcn_mfma_f32_16x16x32_bf16(af, bf0, acc0, 0, 0, 0);
            acc1 = __builtin_amdgcn_mfma_f32_16x16x32_bf16(af, bf1, acc1, 0, 0, 0);
        }
    }

    const float bv0 = bias[wv * 16 + col];
    const float bv1 = bias[(wv + 4) * 16 + col];
#pragma unroll
    for (int r = 0; r < 4; ++r) {
        const int m = m0 + quad * 4 + r;
        __builtin_nontemporal_store(acc0[r] + bv0,
                                    &out[(size_t)m * C_OUT + wv * 16 + col]);
        __builtin_nontemporal_store(acc1[r] + bv1,
                                    &out[(size_t)m * C_OUT + (wv + 4) * 16 + col]);
    }
}

// ---------------------------------------------------------------------------
extern "C" void kernel_launch(void* const* d_in, const int* in_sizes, int n_in,
                              void* d_out, int out_size, void* d_ws, size_t ws_size,
                              hipStream_t stream) {
    const float* h      = (const float*)d_in[0];   // (10000,128)
    const float* X      = (const float*)d_in[1];   // (320000,5)
    const int*   ei     = (const int*)d_in[2];     // (2,320000)
    const float* weight = (const float*)d_in[4];   // (5,128,128) == W(640,128)
    const float* bias   = (const float*)d_in[5];   // (128,)
    float* out = (float*)d_out;

    const int* src = ei;
    const int* dst = ei + N_EDGES;

    // Workspace: offsets [0,64KB) | hb bf16 [64KB,+2.56MB) | Wt bf16 [+4MB)
    //            | R bf16 [+8MB, +20.8MB)
    char* wsb = (char*)d_ws;
    int*            offsets = (int*)wsb;
    uintx2*         hb4     = (uintx2*)(wsb + (64 << 10));
    unsigned short* Wtb     = (unsigned short*)(wsb + (64 << 10) + (4 << 20));
    unsigned int*   R2      = (unsigned int*)(wsb + (64 << 10) + (8 << 20));

    prep<<<1370, 256, 0, stream>>>(h, hb4, weight, Wtb, src, offsets);
    // Instrumentation: 3 identical scatter launches. dur = base + 2*S.
    scatter<<<2500, 256, 0, stream>>>((const unsigned int*)hb4, X, dst, offsets, R2);
    scatter<<<2500, 256, 0, stream>>>((const unsigned int*)hb4, X, dst, offsets, R2);
    scatter<<<2500, 256, 0, stream>>>((const unsigned int*)hb4, X, dst, offsets, R2);
    gemm16<<<625, 256, 0, stream>>>((const unsigned short*)R2, Wtb, bias, out);
}

// Round 14
// 101.103 us; speedup vs baseline: 1.4079x; 1.4079x over previous
//
#include <hip/hip_runtime.h>

#define N_NODES 10000
#define N_EDGES 320000
#define C_IN 128
#define C_OUT 128
#define KDIM 640            // 5 * 128

typedef __attribute__((ext_vector_type(8))) short short8;   // 8 bf16
typedef __attribute__((ext_vector_type(4))) float floatx4;  // MFMA C/D + nt loads
typedef __attribute__((ext_vector_type(2))) unsigned int uintx2;

// ---- bf16 helpers ---------------------------------------------------------
__device__ __forceinline__ unsigned short f2bf(float f) {
    unsigned int b = __float_as_uint(f);
    b = (b + 0x7FFFu + ((b >> 16) & 1u)) >> 16;   // RNE
    return (unsigned short)b;
}
__device__ __forceinline__ unsigned int pack2(float x, float y) {
    return (unsigned int)f2bf(x) | ((unsigned int)f2bf(y) << 16);
}
__device__ __forceinline__ float2 unpack2(unsigned int u) {
    float2 r;
    r.x = __uint_as_float(u << 16);
    r.y = __uint_as_float(u & 0xFFFF0000u);
    return r;
}

// ---------------------------------------------------------------------------
// Kernel 1 (prep): h->bf16, W->Wt bf16 transpose, CSR offsets (r11 verified).
// ---------------------------------------------------------------------------
__global__ __launch_bounds__(256) void prep(
        const float* __restrict__ h, uintx2* __restrict__ hb4,
        const float* __restrict__ W, unsigned short* __restrict__ Wt,
        const int* __restrict__ src, int* __restrict__ offsets) {
    const int bid = blockIdx.x;
    const int tid = threadIdx.x;

    if (bid < 1250) {                       // conv_h: 1250*256 = 320000 exact
        const int t = bid * 256 + tid;
        floatx4 v = __builtin_nontemporal_load(&((const floatx4*)h)[t]);
        uintx2 o;
        o.x = pack2(v.x, v.y);
        o.y = pack2(v.z, v.w);
        hb4[t] = o;
    } else if (bid < 1330) {                // conv_w transpose, 80 blocks
        __shared__ float tile[32][33];
        const int b = bid - 1250;
        const int k0 = (b % 20) * 32, o0 = (b / 20) * 32;
        const int tx = tid & 31, ty = tid >> 5;      // 32 x 8
#pragma unroll
        for (int i = 0; i < 4; ++i)
            tile[ty + 8 * i][tx] =
                __builtin_nontemporal_load(&W[(size_t)(k0 + ty + 8 * i) * C_OUT + o0 + tx]);
        __syncthreads();
#pragma unroll
        for (int i = 0; i < 4; ++i)
            Wt[(size_t)(o0 + ty + 8 * i) * KDIM + k0 + tx] = f2bf(tile[tx][ty + 8 * i]);
    } else {                                // offsets, 40 blocks
        const int n = (bid - 1330) * 256 + tid;
        if (n > N_NODES) return;
        int lo = 0, hi = N_EDGES;
        while (lo < hi) {
            int mid = (lo + hi) >> 1;
            if (src[mid] < n) lo = mid + 1; else hi = mid;
        }
        offsets[n] = lo;
    }
}

// ---------------------------------------------------------------------------
// Kernel 2 (fused): 625 blocks x 512 thr (8 waves) = 16 nodes/block.
//
// Phase 1 (scatter): each wave owns nodes nA = m0+2wv, nB = nA+1, processed
//   INTERLEAVED (round-13 instrumentation: scatter = 15 us at 32 waves/CU
//   but this grid caps at 19.5 waves/CU -> substitute ILP for TLP: the
//   common prefix keeps 8 gathers across 2 independent chains in flight).
//   Scalar metadata (verified r8): node wave-uniform -> dst/X via s_load.
//   Lane = 2 channels (uint bf16x2 gather, 256 B/wave, coalesced from
//   L2-resident hb4). Drain loops handle the degree mismatch.
//
// Phase 2 (GEMM, verified r9/r13): out(16x128) = Rs x Wt^T + bias.
//   Per 64-k chunk: Bs (128x64) staged coalesced b128 from bf16 Wt
//   (2 b128/thread); one 16-col tile per wave (c0 = wv*16), 2 MFMA/chunk.
//   Rs pitch 650 shorts (odd dword), Bs pitch 66 -> <=2-way banks.
//   D row = quad*4+r, col = lane&15 (verified rounds 3-13).
// ---------------------------------------------------------------------------
__global__ __launch_bounds__(512, 4) void fused_spectconv(
        const unsigned int* __restrict__ h2,   // (10000, 64) uint = 2 bf16 ch
        const float* __restrict__ X,           // (320000, 5)
        const int* __restrict__ dst,
        const int* __restrict__ offsets,
        const unsigned short* __restrict__ Wt, // (128, 640) bf16
        const float* __restrict__ bias,
        float* __restrict__ out) {
    __shared__ unsigned short Rs[16][650];     // 20.8 KB
    __shared__ unsigned short Bs[128][66];     // 16.9 KB  (37.7 KB total)

    const int tid  = threadIdx.x;
    const int wv   = __builtin_amdgcn_readfirstlane(tid >> 6);   // scalar 0..7
    const int lane = tid & 63;
    const int m0   = blockIdx.x * 16;          // 625*16 = 10000 exact

    const int nA = m0 + wv * 2;
    const int eA0 = __builtin_amdgcn_readfirstlane(offsets[nA]);
    const int eA1 = __builtin_amdgcn_readfirstlane(offsets[nA + 1]);
    const int eB1 = __builtin_amdgcn_readfirstlane(offsets[nA + 2]);

    float aA0x=0,aA0y=0, aA1x=0,aA1y=0, aA2x=0,aA2y=0, aA3x=0,aA3y=0, aA4x=0,aA4y=0;
    float aB0x=0,aB0y=0, aB1x=0,aB1y=0, aB2x=0,aB2y=0, aB3x=0,aB3y=0, aB4x=0,aB4y=0;

    int eA = eA0, eB = eA1;                    // node B starts at eA1

    // ---- interleaved common prefix: 8 gathers (4+4) in flight ----
    while ((eA + 3 < eA1) && (eB + 3 < eB1)) {
        int dA[4], dB[4];
        unsigned int uA[4], uB[4];
#pragma unroll
        for (int q = 0; q < 4; ++q) { dA[q] = dst[eA + q]; dB[q] = dst[eB + q]; }
#pragma unroll
        for (int q = 0; q < 4; ++q) uA[q] = h2[(size_t)dA[q] * 64 + lane];
#pragma unroll
        for (int q = 0; q < 4; ++q) uB[q] = h2[(size_t)dB[q] * 64 + lane];
#pragma unroll
        for (int q = 0; q < 4; ++q) {
            const float* Xp = X + (size_t)(eA + q) * 5;
            const float x0 = Xp[0], x1 = Xp[1], x2 = Xp[2], x3 = Xp[3], x4 = Xp[4];
            const float2 hv = unpack2(uA[q]);
            aA0x = fmaf(x0, hv.x, aA0x); aA0y = fmaf(x0, hv.y, aA0y);
            aA1x = fmaf(x1, hv.x, aA1x); aA1y = fmaf(x1, hv.y, aA1y);
            aA2x = fmaf(x2, hv.x, aA2x); aA2y = fmaf(x2, hv.y, aA2y);
            aA3x = fmaf(x3, hv.x, aA3x); aA3y = fmaf(x3, hv.y, aA3y);
            aA4x = fmaf(x4, hv.x, aA4x); aA4y = fmaf(x4, hv.y, aA4y);
        }
#pragma unroll
        for (int q = 0; q < 4; ++q) {
            const float* Xp = X + (size_t)(eB + q) * 5;
            const float x0 = Xp[0], x1 = Xp[1], x2 = Xp[2], x3 = Xp[3], x4 = Xp[4];
            const float2 hv = unpack2(uB[q]);
            aB0x = fmaf(x0, hv.x, aB0x); aB0y = fmaf(x0, hv.y, aB0y);
            aB1x = fmaf(x1, hv.x, aB1x); aB1y = fmaf(x1, hv.y, aB1y);
            aB2x = fmaf(x2, hv.x, aB2x); aB2y = fmaf(x2, hv.y, aB2y);
            aB3x = fmaf(x3, hv.x, aB3x); aB3y = fmaf(x3, hv.y, aB3y);
            aB4x = fmaf(x4, hv.x, aB4x); aB4y = fmaf(x4, hv.y, aB4y);
        }
        eA += 4; eB += 4;
    }

    // ---- drain A ----
    for (; eA + 3 < eA1; eA += 4) {
        int d[4]; unsigned int u[4];
#pragma unroll
        for (int q = 0; q < 4; ++q) d[q] = dst[eA + q];
#pragma unroll
        for (int q = 0; q < 4; ++q) u[q] = h2[(size_t)d[q] * 64 + lane];
#pragma unroll
        for (int q = 0; q < 4; ++q) {
            const float* Xp = X + (size_t)(eA + q) * 5;
            const float x0 = Xp[0], x1 = Xp[1], x2 = Xp[2], x3 = Xp[3], x4 = Xp[4];
            const float2 hv = unpack2(u[q]);
            aA0x = fmaf(x0, hv.x, aA0x); aA0y = fmaf(x0, hv.y, aA0y);
            aA1x = fmaf(x1, hv.x, aA1x); aA1y = fmaf(x1, hv.y, aA1y);
            aA2x = fmaf(x2, hv.x, aA2x); aA2y = fmaf(x2, hv.y, aA2y);
            aA3x = fmaf(x3, hv.x, aA3x); aA3y = fmaf(x3, hv.y, aA3y);
            aA4x = fmaf(x4, hv.x, aA4x); aA4y = fmaf(x4, hv.y, aA4y);
        }
    }
    for (; eA < eA1; ++eA) {
        const unsigned int u = h2[(size_t)dst[eA] * 64 + lane];
        const float* Xp = X + (size_t)eA * 5;
        const float x0 = Xp[0], x1 = Xp[1], x2 = Xp[2], x3 = Xp[3], x4 = Xp[4];
        const float2 hv = unpack2(u);
        aA0x = fmaf(x0, hv.x, aA0x); aA0y = fmaf(x0, hv.y, aA0y);
        aA1x = fmaf(x1, hv.x, aA1x); aA1y = fmaf(x1, hv.y, aA1y);
        aA2x = fmaf(x2, hv.x, aA2x); aA2y = fmaf(x2, hv.y, aA2y);
        aA3x = fmaf(x3, hv.x, aA3x); aA3y = fmaf(x3, hv.y, aA3y);
        aA4x = fmaf(x4, hv.x, aA4x); aA4y = fmaf(x4, hv.y, aA4y);
    }

    // ---- drain B ----
    for (; eB + 3 < eB1; eB += 4) {
        int d[4]; unsigned int u[4];
#pragma unroll
        for (int q = 0; q < 4; ++q) d[q] = dst[eB + q];
#pragma unroll
        for (int q = 0; q < 4; ++q) u[q] = h2[(size_t)d[q] * 64 + lane];
#pragma unroll
        for (int q = 0; q < 4; ++q) {
            const float* Xp = X + (size_t)(eB + q) * 5;
            const float x0 = Xp[0], x1 = Xp[1], x2 = Xp[2], x3 = Xp[3], x4 = Xp[4];
            const float2 hv = unpack2(u[q]);
            aB0x = fmaf(x0, hv.x, aB0x); aB0y = fmaf(x0, hv.y, aB0y);
            aB1x = fmaf(x1, hv.x, aB1x); aB1y = fmaf(x1, hv.y, aB1y);
            aB2x = fmaf(x2, hv.x, aB2x); aB2y = fmaf(x2, hv.y, aB2y);
            aB3x = fmaf(x3, hv.x, aB3x); aB3y = fmaf(x3, hv.y, aB3y);
            aB4x = fmaf(x4, hv.x, aB4x); aB4y = fmaf(x4, hv.y, aB4y);
        }
    }
    for (; eB < eB1; ++eB) {
        const unsigned int u = h2[(size_t)dst[eB] * 64 + lane];
        const float* Xp = X + (size_t)eB * 5;
        const float x0 = Xp[0], x1 = Xp[1], x2 = Xp[2], x3 = Xp[3], x4 = Xp[4];
        const float2 hv = unpack2(u);
        aB0x = fmaf(x0, hv.x, aB0x); aB0y = fmaf(x0, hv.y, aB0y);
        aB1x = fmaf(x1, hv.x, aB1x); aB1y = fmaf(x1, hv.y, aB1y);
        aB2x = fmaf(x2, hv.x, aB2x); aB2y = fmaf(x2, hv.y, aB2y);
        aB3x = fmaf(x3, hv.x, aB3x); aB3y = fmaf(x3, hv.y, aB3y);
        aB4x = fmaf(x4, hv.x, aB4x); aB4y = fmaf(x4, hv.y, aB4y);
    }

    // ---- write both Rs rows (uint at dword addr row*325 + k*64 + lane) ----
    {
        const int rA = wv * 2, rB = rA + 1;
        *(unsigned int*)&Rs[rA][0 * 128 + 2 * lane] = pack2(aA0x, aA0y);
        *(unsigned int*)&Rs[rA][1 * 128 + 2 * lane] = pack2(aA1x, aA1y);
        *(unsigned int*)&Rs[rA][2 * 128 + 2 * lane] = pack2(aA2x, aA2y);
        *(unsigned int*)&Rs[rA][3 * 128 + 2 * lane] = pack2(aA3x, aA3y);
        *(unsigned int*)&Rs[rA][4 * 128 + 2 * lane] = pack2(aA4x, aA4y);
        *(unsigned int*)&Rs[rB][0 * 128 + 2 * lane] = pack2(aB0x, aB0y);
        *(unsigned int*)&Rs[rB][1 * 128 + 2 * lane] = pack2(aB1x, aB1y);
        *(unsigned int*)&Rs[rB][2 * 128 + 2 * lane] = pack2(aB2x, aB2y);
        *(unsigned int*)&Rs[rB][3 * 128 + 2 * lane] = pack2(aB3x, aB3y);
        *(unsigned int*)&Rs[rB][4 * 128 + 2 * lane] = pack2(aB4x, aB4y);
    }

    __syncthreads();

    // ---- Phase 2: GEMM ----
    const int col  = lane & 15;
    const int quad = lane >> 4;
    const int c0   = wv * 16;

    floatx4 acc = {0.f, 0.f, 0.f, 0.f};

    for (int chunk = 0; chunk < 10; ++chunk) {
        if (chunk) __syncthreads();
        // Bs: 128 rows x 64 bf16 = 1024 b128 chunks, 2/thread, coalesced.
#pragma unroll
        for (int r = 0; r < 2; ++r) {
            const int c = r * 512 + tid;
            const int row = c >> 3, c8 = c & 7;
            *(short8*)&Bs[row][c8 * 8] =
                *(const short8*)(Wt + (size_t)row * KDIM + chunk * 64 + c8 * 8);
        }
        __syncthreads();

#pragma unroll
        for (int hh = 0; hh < 2; ++hh) {
            const short8 af = *(const short8*)&Rs[col][chunk * 64 + hh * 32 + quad * 8];
            const short8 bf = *(const short8*)&Bs[c0 + col][hh * 32 + quad * 8];
            acc = __builtin_amdgcn_mfma_f32_16x16x32_bf16(af, bf, acc, 0, 0, 0);
        }
    }

    const float bv = bias[c0 + col];
#pragma unroll
    for (int r = 0; r < 4; ++r) {
        const int m = m0 + quad * 4 + r;
        __builtin_nontemporal_store(acc[r] + bv, &out[(size_t)m * C_OUT + c0 + col]);
    }
}

// ---------------------------------------------------------------------------
extern "C" void kernel_launch(void* const* d_in, const int* in_sizes, int n_in,
                              void* d_out, int out_size, void* d_ws, size_t ws_size,
                              hipStream_t stream) {
    const float* h      = (const float*)d_in[0];   // (10000,128)
    const float* X      = (const float*)d_in[1];   // (320000,5)
    const int*   ei     = (const int*)d_in[2];     // (2,320000)
    const float* weight = (const float*)d_in[4];   // (5,128,128) == W(640,128)
    const float* bias   = (const float*)d_in[5];   // (128,)
    float* out = (float*)d_out;

    const int* src = ei;
    const int* dst = ei + N_EDGES;

    // Workspace: offsets [0,64KB) | hb bf16 [64KB,+2.56MB) | Wt bf16 [+4MB)
    char* wsb = (char*)d_ws;
    int*            offsets = (int*)wsb;
    uintx2*         hb4     = (uintx2*)(wsb + (64 << 10));
    unsigned short* Wtb     = (unsigned short*)(wsb + (64 << 10) + (4 << 20));

    prep<<<1370, 256, 0, stream>>>(h, hb4, weight, Wtb, src, offsets);
    fused_spectconv<<<625, 512, 0, stream>>>((const unsigned int*)hb4, X, dst,
                                             offsets, Wtb, bias, out);
}